// Round 9
// baseline (1226.550 us; speedup 1.0000x reference)
//
#include <hip/hip_runtime.h>

// Sizes fixed by the reference.
#define BB 4
#define SS 4096
#define DM 1024
#define HID 64
#define KTOP 204
static constexpr size_t PATTERN_N = (size_t)BB * SS * SS;  // 67108864

// ===== ATTRIBUTION ROUND: internal repeats (idempotent, kept live) =====
#define REP1 8   // k1_mfma
#define REP2 20  // k2_topk
#define REP3 6   // k3_pattern

typedef float f4 __attribute__((ext_vector_type(4)));
typedef float f32x4 __attribute__((ext_vector_type(4)));
typedef _Float16 h8v __attribute__((ext_vector_type(8)));

// d_out scratch layout (float offsets), all < PATTERN_N, overwritten by K3:
#define SCORES_OFF 0
#define WHF_OFF 16384
#define WLF_OFF 49152

// ---------------------------------------------------------------------------
// K0: W1 -> fp16 hi/lo MFMA B-fragments, scaled by 1024 (verified absmax=0).
// ---------------------------------------------------------------------------
__global__ __launch_bounds__(256) void k0_wconv(
    const float* __restrict__ W1, _Float16* __restrict__ whf,
    _Float16* __restrict__ wlf) {
  const int gid = blockIdx.x * 256 + threadIdx.x;  // 8192 total
  const int l = gid & 63;
  const int nt = (gid >> 6) & 3;
  const int k0 = gid >> 8;  // 0..31
  const int kb = k0 * 32 + (l >> 4) * 8;
  const int n = nt * 16 + (l & 15);
  h8v hi, lo;
#pragma unroll
  for (int j = 0; j < 8; ++j) {
    float w = W1[(size_t)(kb + j) * HID + n] * 1024.f;
    _Float16 h = (_Float16)w;
    hi[j] = h;
    lo[j] = (_Float16)((w - (float)h) * 4096.f);
  }
  reinterpret_cast<h8v*>(whf)[(k0 * 4 + nt) * 64 + l] = hi;
  reinterpret_cast<h8v*>(wlf)[(k0 * 4 + nt) * 64 + l] = lo;
}

// ---------------------------------------------------------------------------
// K1: R7 structure (faster of R7/R8): 128 blocks x 4 waves; wave = 32 tokens
// x all 4 N-tiles; fp16 hi/lo 3-MFMA fp32 emu. REP1 outer repeats with
// memory clobber (forces full recompute; stores keep work live).
// ---------------------------------------------------------------------------
__global__ __launch_bounds__(256) void k1_mfma(
    const float* __restrict__ emb, const _Float16* __restrict__ whf,
    const _Float16* __restrict__ wlf, const float* __restrict__ b1,
    const float* __restrict__ W2, const float* __restrict__ b2,
    float* __restrict__ scores) {
  const int tid = threadIdx.x;
  const int l = tid & 63;
  const int wv = tid >> 6;
  const int tokw = blockIdx.x * 128 + wv * 32;  // wave's 32 tokens
  const int lrow = l & 15;
  const int lk8 = (l >> 4) * 8;

  const float* __restrict__ ap0 = emb + (size_t)(tokw + lrow) * DM + lk8;
  const float* __restrict__ ap1 = emb + (size_t)(tokw + 16 + lrow) * DM + lk8;
  const h8v* __restrict__ bhp = reinterpret_cast<const h8v*>(whf);
  const h8v* __restrict__ blp = reinterpret_cast<const h8v*>(wlf);

#pragma unroll 1
  for (int rep = 0; rep < REP1; ++rep) {
    asm volatile("" ::: "memory");  // kill cross-rep CSE; force reloads
    f32x4 acc0[2][4], acc1[2][4];
#pragma unroll
    for (int mt = 0; mt < 2; ++mt)
#pragma unroll
      for (int nt = 0; nt < 4; ++nt) {
        acc0[mt][nt] = (f32x4){0.f, 0.f, 0.f, 0.f};
        acc1[mt][nt] = (f32x4){0.f, 0.f, 0.f, 0.f};
      }

    f4 a0c, a1c, a0c2, a1c2;
    h8v bhc[4], blc[4];
    a0c = *reinterpret_cast<const f4*>(ap0);
    a0c2 = *reinterpret_cast<const f4*>(ap0 + 4);
    a1c = *reinterpret_cast<const f4*>(ap1);
    a1c2 = *reinterpret_cast<const f4*>(ap1 + 4);
#pragma unroll
    for (int nt = 0; nt < 4; ++nt) {
      bhc[nt] = bhp[nt * 64 + l];
      blc[nt] = blp[nt * 64 + l];
    }

#pragma unroll 2
    for (int k0 = 0; k0 < 32; ++k0) {
      f4 a0n, a1n, a0n2, a1n2;
      h8v bhn[4], bln[4];
      if (k0 < 31) {  // prefetch next K-step
        const int koff = (k0 + 1) * 32;
        a0n = *reinterpret_cast<const f4*>(ap0 + koff);
        a0n2 = *reinterpret_cast<const f4*>(ap0 + koff + 4);
        a1n = *reinterpret_cast<const f4*>(ap1 + koff);
        a1n2 = *reinterpret_cast<const f4*>(ap1 + koff + 4);
#pragma unroll
        for (int nt = 0; nt < 4; ++nt) {
          bhn[nt] = bhp[((k0 + 1) * 4 + nt) * 64 + l];
          bln[nt] = blp[((k0 + 1) * 4 + nt) * 64 + l];
        }
      }
      h8v ah[2], al[2];
#pragma unroll
      for (int j = 0; j < 4; ++j) {
        _Float16 h;
        h = (_Float16)a0c[j];  ah[0][j] = h;
        al[0][j] = (_Float16)((a0c[j] - (float)h) * 4096.f);
        h = (_Float16)a0c2[j]; ah[0][4 + j] = h;
        al[0][4 + j] = (_Float16)((a0c2[j] - (float)h) * 4096.f);
        h = (_Float16)a1c[j];  ah[1][j] = h;
        al[1][j] = (_Float16)((a1c[j] - (float)h) * 4096.f);
        h = (_Float16)a1c2[j]; ah[1][4 + j] = h;
        al[1][4 + j] = (_Float16)((a1c2[j] - (float)h) * 4096.f);
      }
#pragma unroll
      for (int mt = 0; mt < 2; ++mt)
#pragma unroll
        for (int nt = 0; nt < 4; ++nt) {
          acc0[mt][nt] = __builtin_amdgcn_mfma_f32_16x16x32_f16(
              ah[mt], bhc[nt], acc0[mt][nt], 0, 0, 0);
          acc1[mt][nt] = __builtin_amdgcn_mfma_f32_16x16x32_f16(
              al[mt], bhc[nt], acc1[mt][nt], 0, 0, 0);
          acc1[mt][nt] = __builtin_amdgcn_mfma_f32_16x16x32_f16(
              ah[mt], blc[nt], acc1[mt][nt], 0, 0, 0);
        }
      if (k0 < 31) {
        a0c = a0n; a0c2 = a0n2; a1c = a1n; a1c2 = a1n2;
#pragma unroll
        for (int nt = 0; nt < 4; ++nt) { bhc[nt] = bhn[nt]; blc[nt] = bln[nt]; }
      }
    }

    float w2v[4], b1v[4];
#pragma unroll
    for (int nt = 0; nt < 4; ++nt) {
      w2v[nt] = W2[nt * 16 + lrow];
      b1v[nt] = b1[nt * 16 + lrow];
    }
    const float bb2 = b2[0];
#pragma unroll
    for (int mt = 0; mt < 2; ++mt)
#pragma unroll
      for (int i = 0; i < 4; ++i) {
        float p = 0.f;
#pragma unroll
        for (int nt = 0; nt < 4; ++nt) {
          float hs = (acc0[mt][nt][i] + 0x1p-12f * acc1[mt][nt][i]) * 0x1p-10f +
                     b1v[nt];
          hs = hs > 0.f ? hs : 0.f;
          p = fmaf(hs, w2v[nt], p);
        }
        p += __shfl_xor(p, 1, 64);
        p += __shfl_xor(p, 2, 64);
        p += __shfl_xor(p, 4, 64);
        p += __shfl_xor(p, 8, 64);
        if (lrow == 0)
          scores[tokw + mt * 16 + (l >> 4) * 4 + i] = p + bb2;
      }
  }
}

// ---------------------------------------------------------------------------
// K2: rank-counting top-k (jax order). REP2 repeats of the count+write
// phase (staging done once; clobber forces LDS re-reads each rep).
// ---------------------------------------------------------------------------
__global__ __launch_bounds__(256) void k2_topk(
    const float* __restrict__ scores, float* __restrict__ out_idx) {
  __shared__ __align__(16) float sc[SS];
  __shared__ int red[256];
  const int tid = threadIdx.x;
  const int b = blockIdx.x >> 6;
  const int ic = blockIdx.x & 63;
  const float* row = scores + (size_t)b * SS;
#pragma unroll
  for (int q = 0; q < 4; ++q) {
    int f = tid + q * 256;  // float4 index
    *reinterpret_cast<f4*>(&sc[f * 4]) =
        *reinterpret_cast<const f4*>(&row[f * 4]);
  }
  __syncthreads();
  const int il = tid & 63;
  const int part = tid >> 6;  // j quarter (wave-uniform)
  const int i = ic * 64 + il;
  const f4* s4 = reinterpret_cast<const f4*>(sc);
#pragma unroll 1
  for (int rep = 0; rep < REP2; ++rep) {
    asm volatile("" ::: "memory");
    const float si = sc[i];
    int cnt = 0;
    for (int j4 = part * 256; j4 < part * 256 + 256; ++j4) {
      f4 v = s4[j4];  // broadcast LDS read
      int j = j4 * 4;
      cnt += (int)(v.x > si) + (int)((v.x == si) & (j + 0 < i));
      cnt += (int)(v.y > si) + (int)((v.y == si) & (j + 1 < i));
      cnt += (int)(v.z > si) + (int)((v.z == si) & (j + 2 < i));
      cnt += (int)(v.w > si) + (int)((v.w == si) & (j + 3 < i));
    }
    red[tid] = cnt;
    __syncthreads();
    if (tid < 64) {
      int tot = red[tid] + red[tid + 64] + red[tid + 128] + red[tid + 192];
      if (tot < KTOP) out_idx[b * KTOP + tot] = (float)(ic * 64 + tid);
    }
    __syncthreads();
  }
}

// ---------------------------------------------------------------------------
// K3: broadcast pattern write, NT stores, 1024 blocks x 16 rows.
// REP3 idempotent repeats (clobber blocks dead-store elimination).
// ---------------------------------------------------------------------------
__global__ __launch_bounds__(256) void k3_pattern(
    const float* __restrict__ out_idx, float* __restrict__ pat) {
  __shared__ __align__(16) float mask[SS];
  const int tid = threadIdx.x;
  const int b  = blockIdx.x >> 8;            // 256 blocks per batch
  const int r0 = (blockIdx.x & 255) * 16;
  const f4 zero = (f4){0.f, 0.f, 0.f, 0.f};
#pragma unroll
  for (int q = 0; q < 4; ++q) {
    int f = tid + q * 256;
    *reinterpret_cast<f4*>(&mask[f * 4]) = zero;
  }
  __syncthreads();
  if (tid < KTOP) {
    int c = (int)out_idx[b * KTOP + tid];
    mask[c] = 1.0f / (float)KTOP;
  }
  __syncthreads();
  const f4 m0 = *reinterpret_cast<const f4*>(&mask[(tid)*4]);
  const f4 m1 = *reinterpret_cast<const f4*>(&mask[(tid + 256) * 4]);
  const f4 m2 = *reinterpret_cast<const f4*>(&mask[(tid + 512) * 4]);
  const f4 m3 = *reinterpret_cast<const f4*>(&mask[(tid + 768) * 4]);
#pragma unroll 1
  for (int rep = 0; rep < REP3; ++rep) {
    asm volatile("" ::: "memory");
    for (int r = 0; r < 16; ++r) {
      f4* p4 = reinterpret_cast<f4*>(pat + ((size_t)b * SS + r0 + r) * SS);
      __builtin_nontemporal_store(m0, &p4[tid]);
      __builtin_nontemporal_store(m1, &p4[tid + 256]);
      __builtin_nontemporal_store(m2, &p4[tid + 512]);
      __builtin_nontemporal_store(m3, &p4[tid + 768]);
    }
  }
}

extern "C" void kernel_launch(void* const* d_in, const int* in_sizes, int n_in,
                              void* d_out, int out_size, void* d_ws,
                              size_t ws_size, hipStream_t stream) {
  const float* emb = (const float*)d_in[0];
  const float* W1  = (const float*)d_in[1];
  const float* b1  = (const float*)d_in[2];
  const float* W2  = (const float*)d_in[3];
  const float* b2  = (const float*)d_in[4];
  float* out = (float*)d_out;
  float* pat     = out;              // [B,S,S] pattern
  float* out_idx = out + PATTERN_N;  // [B,KTOP] indices as float
  float* scores = out + SCORES_OFF;
  _Float16* whf = (_Float16*)(out + WHF_OFF);
  _Float16* wlf = (_Float16*)(out + WLF_OFF);

  k0_wconv<<<dim3(32), dim3(256), 0, stream>>>(W1, whf, wlf);
  k1_mfma<<<dim3((BB * SS) / 128), dim3(256), 0, stream>>>(emb, whf, wlf, b1,
                                                           W2, b2, scores);
  k2_topk<<<dim3(BB * (SS / 64)), dim3(256), 0, stream>>>(scores, out_idx);
  k3_pattern<<<dim3((BB * SS) / 16), dim3(256), 0, stream>>>(out_idx, pat);
}

// Round 10
// 104.247 us; speedup vs baseline: 11.7658x; 11.7658x over previous
//
#include <hip/hip_runtime.h>

// Sizes fixed by the reference.
#define BB 4
#define SS 4096
#define DM 1024
#define HID 64
#define KTOP 204
static constexpr size_t PATTERN_N = (size_t)BB * SS * SS;  // 67108864

typedef float f4 __attribute__((ext_vector_type(4)));
typedef float f32x4 __attribute__((ext_vector_type(4)));
typedef _Float16 h8v __attribute__((ext_vector_type(8)));
typedef unsigned long long ull2 __attribute__((ext_vector_type(2)));

// d_out scratch layout (float offsets), all < PATTERN_N, overwritten by K3:
#define SCORES_OFF 0
#define WHF_OFF 16384
#define WLF_OFF 49152

// ---------------------------------------------------------------------------
// K0: W1 -> fp16 hi/lo MFMA B-fragments, scaled by 1024 (verified absmax=0).
// ---------------------------------------------------------------------------
__global__ __launch_bounds__(256) void k0_wconv(
    const float* __restrict__ W1, _Float16* __restrict__ whf,
    _Float16* __restrict__ wlf) {
  const int gid = blockIdx.x * 256 + threadIdx.x;  // 8192 total
  const int l = gid & 63;
  const int nt = (gid >> 6) & 3;
  const int k0 = gid >> 8;  // 0..31
  const int kb = k0 * 32 + (l >> 4) * 8;
  const int n = nt * 16 + (l & 15);
  h8v hi, lo;
#pragma unroll
  for (int j = 0; j < 8; ++j) {
    float w = W1[(size_t)(kb + j) * HID + n] * 1024.f;
    _Float16 h = (_Float16)w;
    hi[j] = h;
    lo[j] = (_Float16)((w - (float)h) * 4096.f);
  }
  reinterpret_cast<h8v*>(whf)[(k0 * 4 + nt) * 64 + l] = hi;
  reinterpret_cast<h8v*>(wlf)[(k0 * 4 + nt) * 64 + l] = lo;
}

// ---------------------------------------------------------------------------
// K1: R7 exact (~23 us attributed): 128 blocks x 4 waves; wave = 32 tokens x
// 4 N-tiles; fp16 hi/lo 3-MFMA fp32 emulation (absmax=0 verified).
// ---------------------------------------------------------------------------
__global__ __launch_bounds__(256) void k1_mfma(
    const float* __restrict__ emb, const _Float16* __restrict__ whf,
    const _Float16* __restrict__ wlf, const float* __restrict__ b1,
    const float* __restrict__ W2, const float* __restrict__ b2,
    float* __restrict__ scores) {
  const int tid = threadIdx.x;
  const int l = tid & 63;
  const int wv = tid >> 6;
  const int tokw = blockIdx.x * 128 + wv * 32;  // wave's 32 tokens
  const int lrow = l & 15;
  const int lk8 = (l >> 4) * 8;

  const float* __restrict__ ap0 = emb + (size_t)(tokw + lrow) * DM + lk8;
  const float* __restrict__ ap1 = emb + (size_t)(tokw + 16 + lrow) * DM + lk8;
  const h8v* __restrict__ bhp = reinterpret_cast<const h8v*>(whf);
  const h8v* __restrict__ blp = reinterpret_cast<const h8v*>(wlf);

  f32x4 acc0[2][4], acc1[2][4];
#pragma unroll
  for (int mt = 0; mt < 2; ++mt)
#pragma unroll
    for (int nt = 0; nt < 4; ++nt) {
      acc0[mt][nt] = (f32x4){0.f, 0.f, 0.f, 0.f};
      acc1[mt][nt] = (f32x4){0.f, 0.f, 0.f, 0.f};
    }

  f4 a0c, a1c, a0c2, a1c2;
  h8v bhc[4], blc[4];
  a0c = *reinterpret_cast<const f4*>(ap0);
  a0c2 = *reinterpret_cast<const f4*>(ap0 + 4);
  a1c = *reinterpret_cast<const f4*>(ap1);
  a1c2 = *reinterpret_cast<const f4*>(ap1 + 4);
#pragma unroll
  for (int nt = 0; nt < 4; ++nt) {
    bhc[nt] = bhp[nt * 64 + l];
    blc[nt] = blp[nt * 64 + l];
  }

#pragma unroll 2
  for (int k0 = 0; k0 < 32; ++k0) {
    f4 a0n, a1n, a0n2, a1n2;
    h8v bhn[4], bln[4];
    if (k0 < 31) {  // prefetch next K-step
      const int koff = (k0 + 1) * 32;
      a0n = *reinterpret_cast<const f4*>(ap0 + koff);
      a0n2 = *reinterpret_cast<const f4*>(ap0 + koff + 4);
      a1n = *reinterpret_cast<const f4*>(ap1 + koff);
      a1n2 = *reinterpret_cast<const f4*>(ap1 + koff + 4);
#pragma unroll
      for (int nt = 0; nt < 4; ++nt) {
        bhn[nt] = bhp[((k0 + 1) * 4 + nt) * 64 + l];
        bln[nt] = blp[((k0 + 1) * 4 + nt) * 64 + l];
      }
    }
    h8v ah[2], al[2];
#pragma unroll
    for (int j = 0; j < 4; ++j) {
      _Float16 h;
      h = (_Float16)a0c[j];  ah[0][j] = h;
      al[0][j] = (_Float16)((a0c[j] - (float)h) * 4096.f);
      h = (_Float16)a0c2[j]; ah[0][4 + j] = h;
      al[0][4 + j] = (_Float16)((a0c2[j] - (float)h) * 4096.f);
      h = (_Float16)a1c[j];  ah[1][j] = h;
      al[1][j] = (_Float16)((a1c[j] - (float)h) * 4096.f);
      h = (_Float16)a1c2[j]; ah[1][4 + j] = h;
      al[1][4 + j] = (_Float16)((a1c2[j] - (float)h) * 4096.f);
    }
#pragma unroll
    for (int mt = 0; mt < 2; ++mt)
#pragma unroll
      for (int nt = 0; nt < 4; ++nt) {
        acc0[mt][nt] = __builtin_amdgcn_mfma_f32_16x16x32_f16(
            ah[mt], bhc[nt], acc0[mt][nt], 0, 0, 0);
        acc1[mt][nt] = __builtin_amdgcn_mfma_f32_16x16x32_f16(
            al[mt], bhc[nt], acc1[mt][nt], 0, 0, 0);
        acc1[mt][nt] = __builtin_amdgcn_mfma_f32_16x16x32_f16(
            ah[mt], blc[nt], acc1[mt][nt], 0, 0, 0);
      }
    if (k0 < 31) {
      a0c = a0n; a0c2 = a0n2; a1c = a1n; a1c2 = a1n2;
#pragma unroll
      for (int nt = 0; nt < 4; ++nt) { bhc[nt] = bhn[nt]; blc[nt] = bln[nt]; }
    }
  }

  float w2v[4], b1v[4];
#pragma unroll
  for (int nt = 0; nt < 4; ++nt) {
    w2v[nt] = W2[nt * 16 + lrow];
    b1v[nt] = b1[nt * 16 + lrow];
  }
  const float bb2 = b2[0];
#pragma unroll
  for (int mt = 0; mt < 2; ++mt)
#pragma unroll
    for (int i = 0; i < 4; ++i) {
      float p = 0.f;
#pragma unroll
      for (int nt = 0; nt < 4; ++nt) {
        float hs = (acc0[mt][nt][i] + 0x1p-12f * acc1[mt][nt][i]) * 0x1p-10f +
                   b1v[nt];
        hs = hs > 0.f ? hs : 0.f;
        p = fmaf(hs, w2v[nt], p);
      }
      p += __shfl_xor(p, 1, 64);
      p += __shfl_xor(p, 2, 64);
      p += __shfl_xor(p, 4, 64);
      p += __shfl_xor(p, 8, 64);
      if (lrow == 0)
        scores[tokw + mt * 16 + (l >> 4) * 4 + i] = p + bb2;
    }
}

// ---------------------------------------------------------------------------
// K2: top-k by rank counting over monotonic u64 keys.
//   key_j = (mono(s_j) << 32) | (4095 - j); keys all distinct;
//   "j beats i" <=> key_j > key_i  (descending score, ties -> lower index,
//   exactly jax.lax.top_k order). rank_i = #{j: key_j > key_i}.
// 256 blocks x 512 threads (2 waves/SIMD): block = (batch, 64 i's); 8-way
// j-split; ONE v_cmp_gt_u64 + addc per pair (was ~5 VALU in f32 form).
// ---------------------------------------------------------------------------
__global__ __launch_bounds__(512) void k2_topk(
    const float* __restrict__ scores, float* __restrict__ out_idx) {
  __shared__ __align__(16) unsigned long long ku[SS];  // 32 KB keys
  __shared__ int red[512];
  const int tid = threadIdx.x;
  const int b = blockIdx.x >> 6;
  const int ic = blockIdx.x & 63;
  const float* row = scores + (size_t)b * SS;
#pragma unroll
  for (int q = 0; q < 8; ++q) {
    const int j = tid + q * 512;
    unsigned u = __builtin_bit_cast(unsigned, row[j]);
    u ^= (unsigned)((int)u >> 31) | 0x80000000u;  // monotonic map
    ku[j] = ((unsigned long long)u << 32) | (unsigned)(SS - 1 - j);
  }
  __syncthreads();
  const int il = tid & 63;
  const int part = tid >> 6;  // j-eighth (wave-uniform)
  const int i = ic * 64 + il;
  const unsigned long long ki = ku[i];
  const ull2* kp = reinterpret_cast<const ull2*>(ku);
  int cnt = 0;
#pragma unroll 8
  for (int m = part * 256; m < part * 256 + 256; ++m) {
    ull2 v = kp[m];  // broadcast b128 read: 2 keys
    cnt += (int)(v.x > ki) + (int)(v.y > ki);
  }
  red[tid] = cnt;
  __syncthreads();
  if (tid < 64) {
    int tot = 0;
#pragma unroll
    for (int p = 0; p < 8; ++p) tot += red[tid + p * 64];
    if (tot < KTOP) out_idx[b * KTOP + tot] = (float)(ic * 64 + tid);
  }
}

// ---------------------------------------------------------------------------
// K3: attention_pattern[b,i,:] = col_mask[b,:] for all i.
// R3's exact proven config (~35 us attributed): 2048 blocks x 8 rows,
// PLAIN f4 stores (write-combining through L2 at ~7.5 TB/s effective;
// NT stores measured slower: 52-60 us).
// ---------------------------------------------------------------------------
__global__ __launch_bounds__(256) void k3_pattern(
    const float* __restrict__ out_idx, float* __restrict__ pat) {
  __shared__ __align__(16) float mask[SS];
  const int tid = threadIdx.x;
  const int b  = blockIdx.x >> 9;            // 512 blocks per batch
  const int r0 = (blockIdx.x & 511) * 8;
  const f4 zero = (f4){0.f, 0.f, 0.f, 0.f};
#pragma unroll
  for (int q = 0; q < 4; ++q) {
    int f = tid + q * 256;
    *reinterpret_cast<f4*>(&mask[f * 4]) = zero;
  }
  __syncthreads();
  if (tid < KTOP) {
    int c = (int)out_idx[b * KTOP + tid];
    mask[c] = 1.0f / (float)KTOP;
  }
  __syncthreads();
  const f4 m0 = *reinterpret_cast<const f4*>(&mask[(tid)*4]);
  const f4 m1 = *reinterpret_cast<const f4*>(&mask[(tid + 256) * 4]);
  const f4 m2 = *reinterpret_cast<const f4*>(&mask[(tid + 512) * 4]);
  const f4 m3 = *reinterpret_cast<const f4*>(&mask[(tid + 768) * 4]);
  for (int r = 0; r < 8; ++r) {
    f4* p4 = reinterpret_cast<f4*>(pat + ((size_t)b * SS + r0 + r) * SS);
    p4[tid]       = m0;
    p4[tid + 256] = m1;
    p4[tid + 512] = m2;
    p4[tid + 768] = m3;
  }
}

extern "C" void kernel_launch(void* const* d_in, const int* in_sizes, int n_in,
                              void* d_out, int out_size, void* d_ws,
                              size_t ws_size, hipStream_t stream) {
  const float* emb = (const float*)d_in[0];
  const float* W1  = (const float*)d_in[1];
  const float* b1  = (const float*)d_in[2];
  const float* W2  = (const float*)d_in[3];
  const float* b2  = (const float*)d_in[4];
  float* out = (float*)d_out;
  float* pat     = out;              // [B,S,S] pattern
  float* out_idx = out + PATTERN_N;  // [B,KTOP] indices as float
  float* scores = out + SCORES_OFF;
  _Float16* whf = (_Float16*)(out + WHF_OFF);
  _Float16* wlf = (_Float16*)(out + WLF_OFF);

  k0_wconv<<<dim3(32), dim3(256), 0, stream>>>(W1, whf, wlf);
  k1_mfma<<<dim3((BB * SS) / 128), dim3(256), 0, stream>>>(emb, whf, wlf, b1,
                                                           W2, b2, scores);
  k2_topk<<<dim3(BB * 64), dim3(512), 0, stream>>>(scores, out_idx);
  k3_pattern<<<dim3((BB * SS) / 8), dim3(256), 0, stream>>>(out_idx, pat);
}